// Round 4
// baseline (1097.170 us; speedup 1.0000x reference)
//
#include <hip/hip_runtime.h>
#include <math.h>

// CV-photonic circuit: WIRES=4, LAYERS=2, CUTOFF=10, BATCH=2048.
// R17 = R14 structure (fully-inlined passes, compile-time strides,
//  elementwise_fma) narrowed to 1 state/block in v2f so LDS/block =
//  81176 B <= 81920 B -> TWO blocks co-resident per CU (32 waves).
//  R14 (162KB, 1 block/CU) measured 12.7K cy/pass vs ~3.8K throughput
//  floor: the gap is barrier-lockstep drain with no second block to
//  cover it. R15 (pk-asm) and R16 (generic loop) both regressed ->
//  stall-bound, not issue-bound. This buys TLP across blocks instead.
//  Same padded strides (1010,101,10,1) for bank spread.

namespace {

constexpr int NTB = 1024;                 // threads per state block (16 waves)
constexpr int SMEM_STATE = 81176;         // 80792 state + 320 uv + 64 red
constexpr double THETA = 0.7853981633974483096; // pi/4

struct cxf { float x, y; };
typedef float v2f __attribute__((ext_vector_type(2)));

// ws float layout:
// [0,100)       V    (V[k*10+m]; used directly for the V^T gate)
// [100,200)     VT   (VT[k*10+i] = V[i][k]; used for the V gate)
// [200,1200)    Wt   (10 real 10x10, transposed: Wt[n*100+k*10+i]=W_n[i][k])
// [1200,5000)   BSt  cxf[19*100] zero-padded, transposed
// [5000,6600)   ULt  cxf[8*100]: f=0 (L0 UL0, VT-folded), f=4,5,6 (measure)
// [6600,9800)   stage cxf[16*100] raw S_lay (0..7) / D_lay (8..15)
// [9800,15800)  WUt  cxf[30*100]: WU_{b}[n] transposed, id=(b-1)*10+n
// [15872,...)   u    cxf[B*4*10] encoded per-(b,w) vectors
constexpr int U_OFF = 15872;

__device__ __forceinline__ cxf gen_squeeze_f(int i, int j, float zr, float zi){
  if (j == i+2){ float g = 0.5f*sqrtf((float)((i+1)*(i+2))); return {zr*g, -zi*g}; }
  if (i == j+2){ float g = 0.5f*sqrtf((float)((j+1)*(j+2))); return {-zr*g, -zi*g}; }
  return {0.f, 0.f};
}
__device__ __forceinline__ cxf gen_disp_f(int i, int j, float ar, float ai){
  if (i == j+1){ float g = sqrtf((float)i); return {ar*g, ai*g}; }
  if (j == i+1){ float g = sqrtf((float)j); return {-ar*g, ai*g}; }
  return {0.f, 0.f};
}

// Wave-cooperative fixed-schedule fp32 expm: result = exp(M), n x n (n<=10).
__device__ void expm_f32(bool act, int n, cxf* M, cxf* P, cxf* T, cxf* R, int lane){
  const int n2 = n*n;
  if (act){
    for (int e=lane; e<n2; e+=64){ M[e].x *= 0x1p-10f; M[e].y *= 0x1p-10f; }
    for (int e=lane; e<n2; e+=64){
      P[e] = M[e];
      cxf r = M[e];
      if (e % (n+1) == 0) r.x += 1.f;
      R[e] = r;
    }
  }
  __syncthreads();
  for (int t=2; t<=12; ++t){
    if (act){
      float inv = 1.f/(float)t;
      for (int e=lane; e<n2; e+=64){
        int i = e/n, j = e - i*n;
        float ax=0.f, ay=0.f;
        for (int k=0;k<n;k++){
          cxf p = P[i*n+k], m = M[k*n+j];
          ax += p.x*m.x - p.y*m.y;
          ay += p.x*m.y + p.y*m.x;
        }
        T[e] = {ax*inv, ay*inv};
      }
    }
    __syncthreads();
    { cxf* tmp = P; P = T; T = tmp; }
    if (act){ for (int e=lane; e<n2; e+=64){ R[e].x += P[e].x; R[e].y += P[e].y; } }
    __syncthreads();
  }
  for (int s=0; s<10; ++s){
    if (act){
      for (int e=lane; e<n2; e+=64){
        int i = e/n, j = e - i*n;
        float ax=0.f, ay=0.f;
        for (int k=0;k<n;k++){
          cxf p = R[i*n+k], q = R[k*n+j];
          ax += p.x*q.x - p.y*q.y;
          ay += p.x*q.y + p.y*q.x;
        }
        T[e] = {ax, ay};
      }
    }
    __syncthreads();
    { cxf* tmp = R; R = T; T = tmp; }
    __syncthreads();
  }
}

// ------------- Kernel A: 45 expm tasks fully parallel over 12 blocks -------
__global__ __launch_bounds__(256)
void gates_kernel(const float* __restrict__ dmag, const float* __restrict__ dphase,
                  const float* __restrict__ smag, const float* __restrict__ sphase,
                  float* __restrict__ wsf){
  __shared__ double lam[10];
  __shared__ float scr[4][4][200];      // [wave][buf] cxf[100]
  const int tid = threadIdx.x;
  const int wv = tid >> 6, lane = tid & 63, g = blockIdx.x;
  float* ws_V  = wsf;
  float* ws_VT = wsf + 100;
  float* ws_W  = wsf + 200;
  cxf* ws_BS   = (cxf*)(wsf + 1200);
  cxf* ws_stage= (cxf*)(wsf + 6600);

  if (tid < 10){
    double lo = -6.0, hi = 6.0;
    for (int it=0; it<80; ++it){
      double mid = 0.5*(lo+hi);
      int cnt = 0; double q = 1.0;
      for (int i=0;i<10;i++){
        q = -mid - (i ? (double)i/q : 0.0);
        if (fabs(q) < 1e-300) q = -1e-300;
        if (q < 0.0) cnt++;
      }
      if (cnt > tid) hi = mid; else lo = mid;
    }
    double x = 0.5*(lo+hi);
    double p[10];
    p[0] = 1.0; p[1] = x;
    for (int k=1;k<9;k++) p[k+1] = (x*p[k] - sqrt((double)k)*p[k-1]) * (1.0/sqrt((double)(k+1)));
    double nn=0.0; for (int k=0;k<10;k++) nn += p[k]*p[k];
    double inv = 1.0/sqrt(nn);
    lam[tid] = x;
    if (g == 0){
      for (int k=0;k<10;k++){
        float v = (float)(p[k]*inv);
        ws_V[k*10+tid]  = v;
        ws_VT[tid*10+k] = v;
      }
    }
  }
  __syncthreads();

  int t = g*4 + wv;
  bool act = (t < 45);
  int n = 10, bn = 0, ilo = 0;
  if (act && t >= 10 && t < 29){
    bn = t - 10; ilo = bn < 10 ? 0 : bn - 9;
    int ihi = bn < 10 ? bn : 9;
    n = ihi - ilo + 1;
  }
  cxf* M = (cxf*)scr[wv][0];
  cxf* P = (cxf*)scr[wv][1];
  cxf* T = (cxf*)scr[wv][2];
  cxf* R = (cxf*)scr[wv][3];
  if (act){
    if (t < 10){
      float l = (float)lam[t];   // Q = -0.5*(a - ad)
      for (int e=lane; e<100; e+=64){
        int i=e/10, j=e-10*i;
        float v = 0.f;
        if (j == i+1) v = -0.5f*l*sqrtf((float)(i+1));
        else if (i == j+1) v = 0.5f*l*sqrtf((float)i);
        M[e] = {v, 0.f};
      }
    } else if (t < 29){
      for (int e=lane; e<n*n; e+=64){
        int rr=e/n, c=e-n*rr;
        float v = 0.f;
        if (c == rr+1) v = (float)THETA*sqrtf((float)((ilo+rr+1)*(bn-ilo-rr)));
        else if (rr == c+1) v = (float)THETA*sqrtf((float)((ilo+c+1)*(bn-ilo-c)));
        M[e] = {0.f, v};
      }
    } else {
      int idx = t-29, kind = idx>>3, L=(idx>>2)&1, w=idx&3;
      float r_ = kind ? dmag[L*4+w]   : smag[L*4+w];
      float ph = kind ? dphase[L*4+w] : sphase[L*4+w];
      float zr = r_*cosf(ph), zi = r_*sinf(ph);
      for (int e=lane; e<100; e+=64){
        int i=e/10, j=e-10*i;
        M[e] = kind ? gen_disp_f(i,j,zr,zi) : gen_squeeze_f(i,j,zr,zi);
      }
    }
  }
  __syncthreads();
  expm_f32(act, n, M, P, T, R, lane);
  if (act){
    if (t < 10){
      for (int e=lane;e<100;e+=64){
        int i=e/10, j=e-10*i;
        ws_W[t*100 + j*10 + i] = R[e].x;   // transposed, real
      }
    } else if (t < 29){
      for (int e=lane;e<100;e+=64){
        int rr=e/10, c=e-10*rr;
        cxf o; o.x=0.f; o.y=0.f;
        if (rr < n && c < n) o = R[rr*n+c];
        ws_BS[bn*100 + c*10 + rr] = o;     // zero-padded + transposed
      }
    } else {
      int idx = t-29;
      for (int e=lane;e<100;e+=64) ws_stage[idx*100 + e] = R[e];
    }
  }
}

// ---- Kernel A2: UL products, VT fold, and WU_b[n] = W_n * UL_b fusion -----
__global__ __launch_bounds__(512)
void fuse_kernel(float* __restrict__ wsf){
  __shared__ cxf ulraw[8][100];          // raw UL[f] = D*S, [i*10+j]
  const int tid = threadIdx.x, wv = tid>>6, lane = tid&63;
  const cxf* stage = (const cxf*)(wsf + 6600);
  cxf* ws_UL = (cxf*)(wsf + 5000);
  cxf* ws_WU = (cxf*)(wsf + 9800);
  const float* V  = wsf;
  const float* Wt = wsf + 200;
  const cxf* Sm = stage + wv*100;
  const cxf* Dm = stage + (8+wv)*100;
  for (int e=lane; e<100; e+=64){
    int i=e/10, j=e-10*i;
    float ax=0.f, ay=0.f;
    for (int k=0;k<10;k++){
      cxf d=Dm[i*10+k], s=Sm[k*10+j];
      ax += d.x*s.x - d.y*s.y;
      ay += d.x*s.y + d.y*s.x;
    }
    ulraw[wv][e] = {ax, ay};
  }
  __syncthreads();
  // f=0 only: UL0 <- V^T * UL0 (carries L1's V0^T). Two elems per lane.
  cxf t0={0.f,0.f}, t1={0.f,0.f};
  if (wv == 0){
    {
      int e=lane, i=e/10, j=e-10*i;
      float ox=0.f, oy=0.f;
      for (int k=0;k<10;k++){ float v=V[k*10+i]; ox+=v*ulraw[0][k*10+j].x; oy+=v*ulraw[0][k*10+j].y; }
      t0 = {ox, oy};
    }
    if (lane+64 < 100){
      int e=lane+64, i=e/10, j=e-10*i;
      float ox=0.f, oy=0.f;
      for (int k=0;k<10;k++){ float v=V[k*10+i]; ox+=v*ulraw[0][k*10+j].x; oy+=v*ulraw[0][k*10+j].y; }
      t1 = {ox, oy};
    }
  }
  __syncthreads();
  if (wv == 0){
    ulraw[0][lane] = t0;
    if (lane+64 < 100) ulraw[0][lane+64] = t1;
  }
  __syncthreads();
  // Export ULt (transposed) for f in {0,4,5,6}
  for (int e=tid; e<400; e+=512){
    int fi = e/100, r = e-100*fi;
    int f = (fi==0) ? 0 : (3+fi);        // 0,4,5,6
    int i=r/10, j=r-10*i;
    ws_UL[f*100 + j*10 + i] = ulraw[f][i*10+j];
  }
  // Phase 2: WU_b[n] = W_n * ulraw[b], id=(b-1)*10+n, 30 tasks over 8 waves.
  for (int round=0; round<4; ++round){
    int id = round*8 + wv;
    if (id < 30){
      int b = 1 + id/10, n = id - (id/10)*10;
      const cxf* Ub = ulraw[b];
      for (int e=lane; e<100; e+=64){
        int i=e/10, j=e-10*i;
        float ax=0.f, ay=0.f;
        for (int k=0;k<10;k++){
          float w = Wt[n*100 + k*10 + i];   // W_n[i][k]
          ax += w*Ub[k*10+j].x;
          ay += w*Ub[k*10+j].y;
        }
        cxf o; o.x=ax; o.y=ay;
        ws_WU[id*100 + j*10 + i] = o;       // transposed
      }
    }
  }
}

// ------------- Kernel B: per-(b,w) encoding vector u = D*(S*e0), fp32 ------
__global__ __launch_bounds__(128)
void enc_kernel(const float* __restrict__ jets, const float* __restrict__ sscale,
                float* __restrict__ wsf){
  __shared__ float scr[2][4][200];
  __shared__ cxf col[10];
  __shared__ cxf uacc[10];
  const int tid = threadIdx.x, wv = tid>>6, lane = tid&63;
  const int blk = blockIdx.x, b = blk>>2, w = blk&3;

  float eta = jets[b*12 + w*3 + 0];
  float jph = jets[b*12 + w*3 + 1];
  float pt  = jets[b*12 + w*3 + 2];

  cxf* M = (cxf*)scr[wv][0];
  cxf* P = (cxf*)scr[wv][1];
  cxf* T = (cxf*)scr[wv][2];
  cxf* R = (cxf*)scr[wv][3];
  {
    float zr, zi;
    if (wv == 0){ float phs = pt*jph*0.5f; zr = eta*cosf(phs); zi = eta*sinf(phs); }
    else {
      double sc = 10.0/(1.0 + exp(-(double)sscale[0])) + 0.01;
      float mag = (float)sc*pt; zr = mag*cosf(eta); zi = mag*sinf(eta);
    }
    for (int e=lane; e<100; e+=64){
      int i=e/10, j=e-10*i;
      M[e] = wv ? gen_disp_f(i,j,zr,zi) : gen_squeeze_f(i,j,zr,zi);
    }
  }
  __syncthreads();
  expm_f32(true, 10, M, P, T, R, lane);
  cxf* Rs = (cxf*)scr[0][3];
  cxf* Rd = (cxf*)scr[1][3];
  if (tid < 10) col[tid] = Rs[tid*10];           // squeeze column 0
  __syncthreads();
  if (tid < 10){
    float ax=0.f, ay=0.f;
    for (int k=0;k<10;k++){
      cxf d = Rd[tid*10+k], c = col[k];
      ax += d.x*c.x - d.y*c.y;
      ay += d.x*c.y + d.y*c.x;
    }
    uacc[tid] = {ax, ay};
  }
  __syncthreads();
  if (tid < 10){
    float rx, ry;
    if (w == 0){
      rx = 0.f; ry = 0.f;
      for (int k=0;k<10;k++){
        float v = wsf[k*10 + tid];               // (V^T)[tid][k]
        rx += v*uacc[k].x;
        ry += v*uacc[k].y;
      }
    } else { rx = uacc[tid].x; ry = uacc[tid].y; }
    float* u_out = wsf + U_OFF + (b*40 + w*10 + tid)*2;
    u_out[0] = rx;
    u_out[1] = ry;
  }
}

// ---------------- Kernel C: the circuit, 1 state/block, v2f LDS ------------
// Padded digit strides: element (c0,c1,c2,c3) -> c0*1010 + c1*101 + c2*10 + c3.

__device__ __forceinline__ constexpr int WS(int w){
  return w==0 ? 1010 : (w==1 ? 101 : (w==2 ? 10 : 1));
}

#define DECL_ACC2 \
  v2f a0={0.f,0.f}, a1=a0, a2=a0, a3=a0, a4=a0, \
      a5=a0, a6=a0, a7=a0, a8=a0, a9=a0;

#define CK2(i) { v2f u = *(const v2f*)&U[kk+(i)]; \
  a##i = __builtin_elementwise_fma((v2f){u.x,u.x}, vv, a##i); \
  a##i = __builtin_elementwise_fma((v2f){-u.y,u.y}, vs, a##i); }
#define RK2(i) { float u = Mt[kk+(i)]; \
  a##i = __builtin_elementwise_fma((v2f){u,u}, vv, a##i); }
#define BK2(r) { v2f u = *(const v2f*)&Bt[kk+(r)]; \
  a##r = __builtin_elementwise_fma((v2f){u.x,u.x}, vv, a##r); \
  a##r = __builtin_elementwise_fma((v2f){-u.y,u.y}, vs, a##r); }

#define PST2(i) { S[base + (i)*sm] = a##i; }
#define PALL2 PST2(0) PST2(1) PST2(2) PST2(3) PST2(4) PST2(5) PST2(6) PST2(7) PST2(8) PST2(9)
#define BST2(r) if ((r) < sz){ S[wadr] = a##r; wadr += ds; }
#define BALL2 BST2(0) BST2(1) BST2(2) BST2(3) BST2(4) BST2(5) BST2(6) BST2(7) BST2(8) BST2(9)

// Uniform complex gate (UL0).
__device__ __forceinline__ void apply1_c2(v2f* S, const cxf* __restrict__ U, int m, int tid){
  const int sm = WS(m);
  const int r0 = (m==0)?1:0, r1=(m<=1)?2:1, r2=(m<=2)?3:2;
  const int s0 = WS(r0), s1 = WS(r1), s2 = WS(r2);
  if (tid < 1000){
    int c0=tid/100, rem=tid-100*c0, c1=rem/10, c2=rem-10*c1;
    int base = c0*s0 + c1*s1 + c2*s2;
    DECL_ACC2
    #pragma unroll 2
    for (int k=0;k<10;k++){
      v2f vv = S[base + k*sm];
      v2f vs = {vv.y, vv.x};
      int kk = k*10;
      CK2(0) CK2(1) CK2(2) CK2(3) CK2(4) CK2(5) CK2(6) CK2(7) CK2(8) CK2(9)
    }
    PALL2
  }
}

// Uniform real gate (V / V^T).
__device__ __forceinline__ void apply1_r2(v2f* S, const float* __restrict__ Mt, int m, int tid){
  const int sm = WS(m);
  const int r0 = (m==0)?1:0, r1=(m<=1)?2:1, r2=(m<=2)?3:2;
  const int s0 = WS(r0), s1 = WS(r1), s2 = WS(r2);
  if (tid < 1000){
    int c0=tid/100, rem=tid-100*c0, c1=rem/10, c2=rem-10*c1;
    int base = c0*s0 + c1*s1 + c2*s2;
    DECL_ACC2
    #pragma unroll 2
    for (int k=0;k<10;k++){
      v2f vv = S[base + k*sm];
      int kk = k*10;
      RK2(0) RK2(1) RK2(2) RK2(3) RK2(4) RK2(5) RK2(6) RK2(7) RK2(8) RK2(9)
    }
    PALL2
  }
}

// Real conditional gate W(m1,m2): matrix W_n selected by c_{m1}.
__device__ __forceinline__ void applyW2(v2f* S, const float* __restrict__ Wall, int m1, int m2, int tid){
  const int sm  = WS(m2);
  const int sm1 = WS(m1);
  int ra=-1, rb=-1;
  for (int q=0;q<4;q++) if (q!=m1 && q!=m2){ if (ra<0) ra=q; else rb=q; }
  const int sa = WS(ra), sb = WS(rb);
  if (tid < 1000){
    int n = tid/100, rem = tid-100*n, qa = rem/10, qb = rem-10*qa;
    int base = n*sm1 + qa*sa + qb*sb;
    const float* __restrict__ Mt = Wall + n*100;   // transposed W_n
    DECL_ACC2
    #pragma unroll 2
    for (int k=0;k<10;k++){
      v2f vv = S[base + k*sm];
      int kk = k*10;
      RK2(0) RK2(1) RK2(2) RK2(3) RK2(4) RK2(5) RK2(6) RK2(7) RK2(8) RK2(9)
    }
    PALL2
  }
}

// Complex conditional gate on m2 selected by c0: WU_b[n] = W_n*UL_b.
__device__ __forceinline__ void applyWU2(v2f* S, const cxf* __restrict__ WUall, int m2, int tid){
  const int sm = WS(m2);
  const int ra = (m2==1)?2:1;
  const int rb = (m2==3)?2:3;
  const int sa = WS(ra), sb = WS(rb);
  if (tid < 1000){
    int n = tid/100, rem = tid-100*n, qa = rem/10, qb = rem-10*qa;
    int base = n*WS(0) + qa*sa + qb*sb;
    const cxf* __restrict__ U = WUall + n*100;     // transposed complex
    DECL_ACC2
    #pragma unroll 2
    for (int k=0;k<10;k++){
      v2f vv = S[base + k*sm];
      v2f vs = {vv.y, vv.x};
      int kk = k*10;
      CK2(0) CK2(1) CK2(2) CK2(3) CK2(4) CK2(5) CK2(6) CK2(7) CK2(8) CK2(9)
    }
    PALL2
  }
}

// Read-only measure: sum_i i*|(U v)_i|^2 over this thread's fiber.
__device__ __forceinline__ float measure2(const v2f* S, const cxf* __restrict__ U, int m, int tid){
  const int sm = WS(m);
  const int r0 = (m==0)?1:0, r1=(m<=1)?2:1, r2=3;
  const int s0 = WS(r0), s1 = WS(r1), s2 = WS(r2);
  float s = 0.f;
  if (tid < 1000){
    int c0=tid/100, rem=tid-100*c0, c1=rem/10, c2=rem-10*c1;
    int base = c0*s0 + c1*s1 + c2*s2;
    DECL_ACC2
    #pragma unroll 2
    for (int k=0;k<10;k++){
      v2f vv = S[base + k*sm];
      v2f vs = {vv.y, vv.x};
      int kk = k*10;
      CK2(0) CK2(1) CK2(2) CK2(3) CK2(4) CK2(5) CK2(6) CK2(7) CK2(8) CK2(9)
    }
    float p;
    p = a1.x*a1.x + a1.y*a1.y; s += 1.f*p;
    p = a2.x*a2.x + a2.y*a2.y; s += 2.f*p;
    p = a3.x*a3.x + a3.y*a3.y; s += 3.f*p;
    p = a4.x*a4.x + a4.y*a4.y; s += 4.f*p;
    p = a5.x*a5.x + a5.y*a5.y; s += 5.f*p;
    p = a6.x*a6.x + a6.y*a6.y; s += 6.f*p;
    p = a7.x*a7.x + a7.y*a7.y; s += 7.f*p;
    p = a8.x*a8.x + a8.y*a8.y; s += 8.f*p;
    p = a9.x*a9.x + a9.y*a9.y; s += 9.f*p;
  }
  return s;
}

// Beamsplitter: photon-number-conserving anti-diagonal blocks.
__device__ __forceinline__ void applyBS2(v2f* S, const cxf* __restrict__ BSp, int m1, int m2, int tid){
  int ra=-1, rb=-1;
  for (int q=0;q<4;q++) if (q!=m1 && q!=m2){ if (ra<0) ra=q; else rb=q; }
  const int sa = WS(ra), sb = WS(rb);
  const int s1 = WS(m1), s2 = WS(m2);
  const int ds = s1 - s2;
  #pragma unroll 1
  for (int w0=0; w0<2048; w0+=NTB){
    int it = w0 + tid;
    if (it < 1900){
      int bn = it/100, rest = it-100*bn;
      int ilo = bn<10?0:bn-9, ihi = bn<10?bn:9, sz = ihi-ilo+1;
      int ca = rest/10, cb = rest-10*ca;
      int base = ca*sa + cb*sb;
      const cxf* __restrict__ Bt = BSp + bn*100;   // transposed, zero-padded
      DECL_ACC2
      int radr = base + ilo*s1 + (bn-ilo)*s2;
      int kk = 0;
      #pragma unroll 1
      for (int c=0;c<sz;c++){
        v2f vv = S[radr];
        v2f vs = {vv.y, vv.x};
        BK2(0) BK2(1) BK2(2) BK2(3) BK2(4) BK2(5) BK2(6) BK2(7) BK2(8) BK2(9)
        radr += ds; kk += 10;
      }
      int wadr = base + ilo*s1 + (bn-ilo)*s2;
      BALL2
    }
  }
}

__global__ __launch_bounds__(NTB)
__attribute__((amdgpu_waves_per_eu(8)))
void state_kernel(const float* __restrict__ wd, const float* __restrict__ bd,
                  const float* __restrict__ wsf, float* __restrict__ out){
  extern __shared__ __align__(16) char smem[];
  v2f* S    = (v2f*)smem;                 // 10099 v2f (80792 B)
  cxf* uv   = (cxf*)(smem + 80792);       // 4*10 encoding vectors
  float* red = (float*)(smem + 81112);    // 16

  const float* __restrict__ V   = wsf;            // for V^T gate
  const float* __restrict__ VT  = wsf + 100;      // for V gate
  const float* __restrict__ W   = wsf + 200;
  const cxf*   __restrict__ BSm = (const cxf*)(wsf + 1200);
  const cxf*   __restrict__ UL  = (const cxf*)(wsf + 5000);
  const cxf*   __restrict__ WU  = (const cxf*)(wsf + 9800);
  const cxf*   __restrict__ uw  = (const cxf*)(wsf + U_OFF);

  const int tid = threadIdx.x, wv = tid>>6, lane = tid&63;
  const int b = blockIdx.x;

  if (tid < 40) uv[tid] = uw[b*40 + tid];
  __syncthreads();

  // Init: product state S = u0 (x) u1 (x) u2 (x) u3  (L0's V0^T folded in u0)
  for (int e=tid; e<10000; e+=NTB){
    int c0=e/1000, r_=e-1000*c0, c1=r_/100, r2_=r_-100*c1, c2=r2_/10, c3=r2_-10*c2;
    cxf A = uv[c0], B = uv[10+c1], C = uv[20+c2], D = uv[30+c3];
    float pr = A.x*B.x - A.y*B.y, pi = A.x*B.y + A.y*B.x;
    float qr = pr*C.x - pi*C.y,  qi = pr*C.y + pi*C.x;
    v2f o; o.x = qr*D.x - qi*D.y; o.y = qr*D.y + qi*D.x;
    S[c0*1010 + c1*101 + c2*10 + c3] = o;
  }
  __syncthreads();

  // ---------------- Layer 0 ----------------
  applyW2(S, W, 0, 1, tid); __syncthreads();
  applyW2(S, W, 0, 2, tid); __syncthreads();
  applyW2(S, W, 0, 3, tid); __syncthreads();
  apply1_r2(S, VT, 0, tid); __syncthreads();      // V0
  apply1_r2(S, V, 1, tid);  __syncthreads();      // V1^T
  applyW2(S, W, 1, 2, tid); __syncthreads();
  applyW2(S, W, 1, 3, tid); __syncthreads();
  apply1_r2(S, VT, 1, tid); __syncthreads();      // V1
  apply1_r2(S, V, 2, tid);  __syncthreads();      // V2^T
  applyW2(S, W, 2, 3, tid); __syncthreads();
  apply1_r2(S, VT, 2, tid); __syncthreads();      // V2
  applyBS2(S, BSm, 0, 1, tid); __syncthreads();
  applyBS2(S, BSm, 1, 2, tid); __syncthreads();
  applyBS2(S, BSm, 2, 3, tid); __syncthreads();
  applyBS2(S, BSm, 3, 0, tid); __syncthreads();
  apply1_c2(S, UL, 0, tid); __syncthreads();      // UL0_L0 (carries L1's V0^T)

  // ---------------- Layer 1 ----------------
  applyWU2(S, WU,        1, tid); __syncthreads();
  applyWU2(S, WU + 1000, 2, tid); __syncthreads();
  applyWU2(S, WU + 2000, 3, tid); __syncthreads();
  apply1_r2(S, VT, 0, tid); __syncthreads();      // V0
  apply1_r2(S, V, 1, tid);  __syncthreads();      // V1^T
  applyW2(S, W, 1, 2, tid); __syncthreads();
  applyW2(S, W, 1, 3, tid); __syncthreads();
  apply1_r2(S, VT, 1, tid); __syncthreads();      // V1
  apply1_r2(S, V, 2, tid);  __syncthreads();      // V2^T
  applyW2(S, W, 2, 3, tid); __syncthreads();
  apply1_r2(S, VT, 2, tid); __syncthreads();      // V2
  applyBS2(S, BSm, 0, 1, tid); __syncthreads();
  applyBS2(S, BSm, 1, 2, tid); __syncthreads();
  applyBS2(S, BSm, 2, 3, tid); __syncthreads();
  applyBS2(S, BSm, 3, 0, tid); __syncthreads();

  // Fused measurement: UL[L1,m] applied read-only; UL[L1,3] dropped.
  float w0 = wd[0], w1 = wd[1], w2 = wd[2];
  float acc = 0.f;
  acc += w0 * measure2(S, UL + 400, 0, tid);
  acc += w1 * measure2(S, UL + 500, 1, tid);
  acc += w2 * measure2(S, UL + 600, 2, tid);

  for (int off=32; off; off>>=1) acc += __shfl_down(acc, off, 64);
  if (lane == 0) red[wv] = acc;
  __syncthreads();
  if (tid == 0){
    float s = 0.f;
    for (int i=0;i<16;i++) s += red[i];
    out[b] = s + bd[0];
  }
}

} // anonymous namespace

extern "C" void kernel_launch(void* const* d_in, const int* in_sizes, int n_in,
                              void* d_out, int out_size, void* d_ws, size_t ws_size,
                              hipStream_t stream){
  const float* jets   = (const float*)d_in[0];
  const float* sscale = (const float*)d_in[1];
  const float* dmag   = (const float*)d_in[2];
  const float* dphase = (const float*)d_in[3];
  const float* smag   = (const float*)d_in[4];
  const float* sphase = (const float*)d_in[5];
  const float* wd     = (const float*)d_in[6];
  const float* bd     = (const float*)d_in[7];
  float* out = (float*)d_out;
  float* wsf = (float*)d_ws;
  int B = in_sizes[0] / 12;

  (void)hipFuncSetAttribute(reinterpret_cast<const void*>(&state_kernel),
                            hipFuncAttributeMaxDynamicSharedMemorySize, SMEM_STATE);

  gates_kernel<<<12, 256, 0, stream>>>(dmag, dphase, smag, sphase, wsf);
  fuse_kernel<<<1, 512, 0, stream>>>(wsf);
  enc_kernel<<<B*4, 128, 0, stream>>>(jets, sscale, wsf);
  state_kernel<<<B, NTB, SMEM_STATE, stream>>>(wd, bd, wsf, out);
}

// Round 5
// 856.738 us; speedup vs baseline: 1.2806x; 1.2806x over previous
//
#include <hip/hip_runtime.h>
#include <math.h>

// CV-photonic circuit: WIRES=4, LAYERS=2, CUTOFF=10, BATCH=2048.
// R18 = R14 (2 states/block v4f, padded strides, best at 721us) +
//  latency restructure of pass bodies ONLY:
//  (1) all 10 ds_read_b128 hoisted to pass start, k-loop fully unrolled
//      -> 1 lgkmcnt wait/pass (was 5 with unroll-2).
//  (2) matrix rows loaded as 16B v4f (complex row = 5 dwordx4, real rows
//      paired) -> conditional-pass VMEM instr count halved.
//  Mechanism: R14 is convoy/latency-bound (11.7K cy/pass vs ~4K port
//  floors); fewer waits + fewer vmem instrs shortens the serial chain.
//  R15(pk-asm)/R16(generic loop)/R17(2 blocks/CU) all regressed - the
//  2-state amortized structure is the winner; only the wait structure
//  changes here.

namespace {

constexpr int NTB = 1024;                 // threads per state block (16 waves)
constexpr int SMEM_STATE = 162352;        // 161584 state + 640 uv + 128 red
constexpr double THETA = 0.7853981633974483096; // pi/4

struct cxf { float x, y; };
typedef float v2f __attribute__((ext_vector_type(2)));
typedef float v4f __attribute__((ext_vector_type(4)));

// ws float layout:
// [0,100)       V    (V[k*10+m]; used directly for the V^T gate)
// [100,200)     VT   (VT[k*10+i] = V[i][k]; used for the V gate)
// [200,1200)    Wt   (10 real 10x10, transposed: Wt[n*100+k*10+i]=W_n[i][k])
// [1200,5000)   BSt  cxf[19*100] zero-padded, transposed
// [5000,6600)   ULt  cxf[8*100]: f=0 (L0 UL0, VT-folded), f=4,5,6 (measure)
// [6600,9800)   stage cxf[16*100] raw S_lay (0..7) / D_lay (8..15)
// [9800,15800)  WUt  cxf[30*100]: WU_{b}[n] transposed, id=(b-1)*10+n
// [15872,...)   u    cxf[B*4*10] encoded per-(b,w) vectors
constexpr int U_OFF = 15872;

__device__ __forceinline__ cxf gen_squeeze_f(int i, int j, float zr, float zi){
  if (j == i+2){ float g = 0.5f*sqrtf((float)((i+1)*(i+2))); return {zr*g, -zi*g}; }
  if (i == j+2){ float g = 0.5f*sqrtf((float)((j+1)*(j+2))); return {-zr*g, -zi*g}; }
  return {0.f, 0.f};
}
__device__ __forceinline__ cxf gen_disp_f(int i, int j, float ar, float ai){
  if (i == j+1){ float g = sqrtf((float)i); return {ar*g, ai*g}; }
  if (j == i+1){ float g = sqrtf((float)j); return {-ar*g, ai*g}; }
  return {0.f, 0.f};
}

// Wave-cooperative fixed-schedule fp32 expm: result = exp(M), n x n (n<=10).
__device__ void expm_f32(bool act, int n, cxf* M, cxf* P, cxf* T, cxf* R, int lane){
  const int n2 = n*n;
  if (act){
    for (int e=lane; e<n2; e+=64){ M[e].x *= 0x1p-10f; M[e].y *= 0x1p-10f; }
    for (int e=lane; e<n2; e+=64){
      P[e] = M[e];
      cxf r = M[e];
      if (e % (n+1) == 0) r.x += 1.f;
      R[e] = r;
    }
  }
  __syncthreads();
  for (int t=2; t<=12; ++t){
    if (act){
      float inv = 1.f/(float)t;
      for (int e=lane; e<n2; e+=64){
        int i = e/n, j = e - i*n;
        float ax=0.f, ay=0.f;
        for (int k=0;k<n;k++){
          cxf p = P[i*n+k], m = M[k*n+j];
          ax += p.x*m.x - p.y*m.y;
          ay += p.x*m.y + p.y*m.x;
        }
        T[e] = {ax*inv, ay*inv};
      }
    }
    __syncthreads();
    { cxf* tmp = P; P = T; T = tmp; }
    if (act){ for (int e=lane; e<n2; e+=64){ R[e].x += P[e].x; R[e].y += P[e].y; } }
    __syncthreads();
  }
  for (int s=0; s<10; ++s){
    if (act){
      for (int e=lane; e<n2; e+=64){
        int i = e/n, j = e - i*n;
        float ax=0.f, ay=0.f;
        for (int k=0;k<n;k++){
          cxf p = R[i*n+k], q = R[k*n+j];
          ax += p.x*q.x - p.y*q.y;
          ay += p.x*q.y + p.y*q.x;
        }
        T[e] = {ax, ay};
      }
    }
    __syncthreads();
    { cxf* tmp = R; R = T; T = tmp; }
    __syncthreads();
  }
}

// ------------- Kernel A: 45 expm tasks fully parallel over 12 blocks -------
__global__ __launch_bounds__(256)
void gates_kernel(const float* __restrict__ dmag, const float* __restrict__ dphase,
                  const float* __restrict__ smag, const float* __restrict__ sphase,
                  float* __restrict__ wsf){
  __shared__ double lam[10];
  __shared__ float scr[4][4][200];      // [wave][buf] cxf[100]
  const int tid = threadIdx.x;
  const int wv = tid >> 6, lane = tid & 63, g = blockIdx.x;
  float* ws_V  = wsf;
  float* ws_VT = wsf + 100;
  float* ws_W  = wsf + 200;
  cxf* ws_BS   = (cxf*)(wsf + 1200);
  cxf* ws_stage= (cxf*)(wsf + 6600);

  if (tid < 10){
    double lo = -6.0, hi = 6.0;
    for (int it=0; it<80; ++it){
      double mid = 0.5*(lo+hi);
      int cnt = 0; double q = 1.0;
      for (int i=0;i<10;i++){
        q = -mid - (i ? (double)i/q : 0.0);
        if (fabs(q) < 1e-300) q = -1e-300;
        if (q < 0.0) cnt++;
      }
      if (cnt > tid) hi = mid; else lo = mid;
    }
    double x = 0.5*(lo+hi);
    double p[10];
    p[0] = 1.0; p[1] = x;
    for (int k=1;k<9;k++) p[k+1] = (x*p[k] - sqrt((double)k)*p[k-1]) * (1.0/sqrt((double)(k+1)));
    double nn=0.0; for (int k=0;k<10;k++) nn += p[k]*p[k];
    double inv = 1.0/sqrt(nn);
    lam[tid] = x;
    if (g == 0){
      for (int k=0;k<10;k++){
        float v = (float)(p[k]*inv);
        ws_V[k*10+tid]  = v;
        ws_VT[tid*10+k] = v;
      }
    }
  }
  __syncthreads();

  int t = g*4 + wv;
  bool act = (t < 45);
  int n = 10, bn = 0, ilo = 0;
  if (act && t >= 10 && t < 29){
    bn = t - 10; ilo = bn < 10 ? 0 : bn - 9;
    int ihi = bn < 10 ? bn : 9;
    n = ihi - ilo + 1;
  }
  cxf* M = (cxf*)scr[wv][0];
  cxf* P = (cxf*)scr[wv][1];
  cxf* T = (cxf*)scr[wv][2];
  cxf* R = (cxf*)scr[wv][3];
  if (act){
    if (t < 10){
      float l = (float)lam[t];   // Q = -0.5*(a - ad)
      for (int e=lane; e<100; e+=64){
        int i=e/10, j=e-10*i;
        float v = 0.f;
        if (j == i+1) v = -0.5f*l*sqrtf((float)(i+1));
        else if (i == j+1) v = 0.5f*l*sqrtf((float)i);
        M[e] = {v, 0.f};
      }
    } else if (t < 29){
      for (int e=lane; e<n*n; e+=64){
        int rr=e/n, c=e-n*rr;
        float v = 0.f;
        if (c == rr+1) v = (float)THETA*sqrtf((float)((ilo+rr+1)*(bn-ilo-rr)));
        else if (rr == c+1) v = (float)THETA*sqrtf((float)((ilo+c+1)*(bn-ilo-c)));
        M[e] = {0.f, v};
      }
    } else {
      int idx = t-29, kind = idx>>3, L=(idx>>2)&1, w=idx&3;
      float r_ = kind ? dmag[L*4+w]   : smag[L*4+w];
      float ph = kind ? dphase[L*4+w] : sphase[L*4+w];
      float zr = r_*cosf(ph), zi = r_*sinf(ph);
      for (int e=lane; e<100; e+=64){
        int i=e/10, j=e-10*i;
        M[e] = kind ? gen_disp_f(i,j,zr,zi) : gen_squeeze_f(i,j,zr,zi);
      }
    }
  }
  __syncthreads();
  expm_f32(act, n, M, P, T, R, lane);
  if (act){
    if (t < 10){
      for (int e=lane;e<100;e+=64){
        int i=e/10, j=e-10*i;
        ws_W[t*100 + j*10 + i] = R[e].x;   // transposed, real
      }
    } else if (t < 29){
      for (int e=lane;e<100;e+=64){
        int rr=e/10, c=e-10*rr;
        cxf o; o.x=0.f; o.y=0.f;
        if (rr < n && c < n) o = R[rr*n+c];
        ws_BS[bn*100 + c*10 + rr] = o;     // zero-padded + transposed
      }
    } else {
      int idx = t-29;
      for (int e=lane;e<100;e+=64) ws_stage[idx*100 + e] = R[e];
    }
  }
}

// ---- Kernel A2: UL products, VT fold, and WU_b[n] = W_n * UL_b fusion -----
__global__ __launch_bounds__(512)
void fuse_kernel(float* __restrict__ wsf){
  __shared__ cxf ulraw[8][100];          // raw UL[f] = D*S, [i*10+j]
  const int tid = threadIdx.x, wv = tid>>6, lane = tid&63;
  const cxf* stage = (const cxf*)(wsf + 6600);
  cxf* ws_UL = (cxf*)(wsf + 5000);
  cxf* ws_WU = (cxf*)(wsf + 9800);
  const float* V  = wsf;
  const float* Wt = wsf + 200;
  const cxf* Sm = stage + wv*100;
  const cxf* Dm = stage + (8+wv)*100;
  for (int e=lane; e<100; e+=64){
    int i=e/10, j=e-10*i;
    float ax=0.f, ay=0.f;
    for (int k=0;k<10;k++){
      cxf d=Dm[i*10+k], s=Sm[k*10+j];
      ax += d.x*s.x - d.y*s.y;
      ay += d.x*s.y + d.y*s.x;
    }
    ulraw[wv][e] = {ax, ay};
  }
  __syncthreads();
  // f=0 only: UL0 <- V^T * UL0 (carries L1's V0^T). Two elems per lane.
  cxf t0={0.f,0.f}, t1={0.f,0.f};
  if (wv == 0){
    {
      int e=lane, i=e/10, j=e-10*i;
      float ox=0.f, oy=0.f;
      for (int k=0;k<10;k++){ float v=V[k*10+i]; ox+=v*ulraw[0][k*10+j].x; oy+=v*ulraw[0][k*10+j].y; }
      t0 = {ox, oy};
    }
    if (lane+64 < 100){
      int e=lane+64, i=e/10, j=e-10*i;
      float ox=0.f, oy=0.f;
      for (int k=0;k<10;k++){ float v=V[k*10+i]; ox+=v*ulraw[0][k*10+j].x; oy+=v*ulraw[0][k*10+j].y; }
      t1 = {ox, oy};
    }
  }
  __syncthreads();
  if (wv == 0){
    ulraw[0][lane] = t0;
    if (lane+64 < 100) ulraw[0][lane+64] = t1;
  }
  __syncthreads();
  // Export ULt (transposed) for f in {0,4,5,6}
  for (int e=tid; e<400; e+=512){
    int fi = e/100, r = e-100*fi;
    int f = (fi==0) ? 0 : (3+fi);        // 0,4,5,6
    int i=r/10, j=r-10*i;
    ws_UL[f*100 + j*10 + i] = ulraw[f][i*10+j];
  }
  // Phase 2: WU_b[n] = W_n * ulraw[b], id=(b-1)*10+n, 30 tasks over 8 waves.
  for (int round=0; round<4; ++round){
    int id = round*8 + wv;
    if (id < 30){
      int b = 1 + id/10, n = id - (id/10)*10;
      const cxf* Ub = ulraw[b];
      for (int e=lane; e<100; e+=64){
        int i=e/10, j=e-10*i;
        float ax=0.f, ay=0.f;
        for (int k=0;k<10;k++){
          float w = Wt[n*100 + k*10 + i];   // W_n[i][k]
          ax += w*Ub[k*10+j].x;
          ay += w*Ub[k*10+j].y;
        }
        cxf o; o.x=ax; o.y=ay;
        ws_WU[id*100 + j*10 + i] = o;       // transposed
      }
    }
  }
}

// ------------- Kernel B: per-(b,w) encoding vector u = D*(S*e0), fp32 ------
__global__ __launch_bounds__(128)
void enc_kernel(const float* __restrict__ jets, const float* __restrict__ sscale,
                float* __restrict__ wsf){
  __shared__ float scr[2][4][200];
  __shared__ cxf col[10];
  __shared__ cxf uacc[10];
  const int tid = threadIdx.x, wv = tid>>6, lane = tid&63;
  const int blk = blockIdx.x, b = blk>>2, w = blk&3;

  float eta = jets[b*12 + w*3 + 0];
  float jph = jets[b*12 + w*3 + 1];
  float pt  = jets[b*12 + w*3 + 2];

  cxf* M = (cxf*)scr[wv][0];
  cxf* P = (cxf*)scr[wv][1];
  cxf* T = (cxf*)scr[wv][2];
  cxf* R = (cxf*)scr[wv][3];
  {
    float zr, zi;
    if (wv == 0){ float phs = pt*jph*0.5f; zr = eta*cosf(phs); zi = eta*sinf(phs); }
    else {
      double sc = 10.0/(1.0 + exp(-(double)sscale[0])) + 0.01;
      float mag = (float)sc*pt; zr = mag*cosf(eta); zi = mag*sinf(eta);
    }
    for (int e=lane; e<100; e+=64){
      int i=e/10, j=e-10*i;
      M[e] = wv ? gen_disp_f(i,j,zr,zi) : gen_squeeze_f(i,j,zr,zi);
    }
  }
  __syncthreads();
  expm_f32(true, 10, M, P, T, R, lane);
  cxf* Rs = (cxf*)scr[0][3];
  cxf* Rd = (cxf*)scr[1][3];
  if (tid < 10) col[tid] = Rs[tid*10];           // squeeze column 0
  __syncthreads();
  if (tid < 10){
    float ax=0.f, ay=0.f;
    for (int k=0;k<10;k++){
      cxf d = Rd[tid*10+k], c = col[k];
      ax += d.x*c.x - d.y*c.y;
      ay += d.x*c.y + d.y*c.x;
    }
    uacc[tid] = {ax, ay};
  }
  __syncthreads();
  if (tid < 10){
    float rx, ry;
    if (w == 0){
      rx = 0.f; ry = 0.f;
      for (int k=0;k<10;k++){
        float v = wsf[k*10 + tid];               // (V^T)[tid][k]
        rx += v*uacc[k].x;
        ry += v*uacc[k].y;
      }
    } else { rx = uacc[tid].x; ry = uacc[tid].y; }
    float* u_out = wsf + U_OFF + (b*40 + w*10 + tid)*2;
    u_out[0] = rx;
    u_out[1] = ry;
  }
}

// ---------------- Kernel C: the circuit, 2 states/block, v4f LDS -----------
// Padded digit strides: element (c0,c1,c2,c3) -> c0*1010 + c1*101 + c2*10 + c3.
// idx%8 = (2c0+5c1+2c2+c3)%8 spreads 16B slots across the 128B LDS row.
__device__ __forceinline__ constexpr int WS(int w){
  return w==0 ? 1010 : (w==1 ? 101 : (w==2 ? 10 : 1));
}

#define DECL_ACC4 \
  v4f a0={0.f,0.f,0.f,0.f}, a1=a0, a2=a0, a3=a0, a4=a0, \
      a5=a0, a6=a0, a7=a0, a8=a0, a9=a0;

// hoisted state reads: all 10 ds_read_b128 issued before any math
#define LDS_RD10 \
  v4f r0=S[base], r1=S[base+sm], r2=S[base+2*sm], r3=S[base+3*sm], r4=S[base+4*sm], \
      r5=S[base+5*sm], r6=S[base+6*sm], r7=S[base+7*sm], r8=S[base+8*sm], r9=S[base+9*sm];

// complex element fma on both interleaved states
#define CE(i,ur,ui) \
  a##i = __builtin_elementwise_fma((v4f){(ur),(ur),(ur),(ur)}, vv, a##i); \
  a##i = __builtin_elementwise_fma((v4f){-(ui),(ui),-(ui),(ui)}, vs, a##i);
#define RE(i,u) a##i = __builtin_elementwise_fma((v4f){(u),(u),(u),(u)}, vv, a##i);

// one complex k-step: matrix row krow loaded as 5 dwordx4 (10 cxf)
#define CSTEP(rk,krow) { \
  const v4f* Up = (const v4f*)(U + (krow)*10); \
  v4f q0=Up[0],q1=Up[1],q2=Up[2],q3=Up[3],q4=Up[4]; \
  v4f vv=rk, vs=__builtin_shufflevector(rk,rk,1,0,3,2); \
  CE(0,q0.x,q0.y) CE(1,q0.z,q0.w) CE(2,q1.x,q1.y) CE(3,q1.z,q1.w) \
  CE(4,q2.x,q2.y) CE(5,q2.z,q2.w) CE(6,q3.x,q3.y) CE(7,q3.z,q3.w) \
  CE(8,q4.x,q4.y) CE(9,q4.z,q4.w) }
#define CSTEP_ALL CSTEP(r0,0) CSTEP(r1,1) CSTEP(r2,2) CSTEP(r3,3) CSTEP(r4,4) \
  CSTEP(r5,5) CSTEP(r6,6) CSTEP(r7,7) CSTEP(r8,8) CSTEP(r9,9)

// two real k-steps: rows krow,krow+1 (20 floats) loaded as 5 dwordx4
#define RSTEP2(ra_,rb_,krow) { \
  const v4f* Mp = (const v4f*)(Mt + (krow)*10); \
  v4f q0=Mp[0],q1=Mp[1],q2=Mp[2],q3=Mp[3],q4=Mp[4]; \
  { v4f vv=ra_; RE(0,q0.x) RE(1,q0.y) RE(2,q0.z) RE(3,q0.w) RE(4,q1.x) \
                RE(5,q1.y) RE(6,q1.z) RE(7,q1.w) RE(8,q2.x) RE(9,q2.y) } \
  { v4f vv=rb_; RE(0,q2.z) RE(1,q2.w) RE(2,q3.x) RE(3,q3.y) RE(4,q3.z) \
                RE(5,q3.w) RE(6,q4.x) RE(7,q4.y) RE(8,q4.z) RE(9,q4.w) } }
#define RSTEP_ALL RSTEP2(r0,r1,0) RSTEP2(r2,r3,2) RSTEP2(r4,r5,4) \
  RSTEP2(r6,r7,6) RSTEP2(r8,r9,8)

#define PST4(i) { S[base + (i)*sm] = a##i; }
#define PALL4 PST4(0) PST4(1) PST4(2) PST4(3) PST4(4) PST4(5) PST4(6) PST4(7) PST4(8) PST4(9)
#define BSTQ(r) if ((r) < sz){ S[wadr] = a##r; wadr += ds; }
#define BSTQ_ALL BSTQ(0) BSTQ(1) BSTQ(2) BSTQ(3) BSTQ(4) BSTQ(5) BSTQ(6) BSTQ(7) BSTQ(8) BSTQ(9)

// Uniform/conditional complex gate (UL0 / WU): U points at this thread's matrix.
__device__ __forceinline__ void apply1_c4(v4f* S, const cxf* __restrict__ U, int m, int tid){
  const int sm = WS(m);
  const int x0 = (m==0)?1:0, x1=(m<=1)?2:1, x2=(m<=2)?3:2;
  const int s0 = WS(x0), s1 = WS(x1), s2 = WS(x2);
  if (tid < 1000){
    int c0=tid/100, rem=tid-100*c0, c1=rem/10, c2=rem-10*c1;
    int base = c0*s0 + c1*s1 + c2*s2;
    LDS_RD10
    DECL_ACC4
    CSTEP_ALL
    PALL4
  }
}

// Uniform real gate (V / V^T).
__device__ __forceinline__ void apply1_r4(v4f* S, const float* __restrict__ Mt, int m, int tid){
  const int sm = WS(m);
  const int x0 = (m==0)?1:0, x1=(m<=1)?2:1, x2=(m<=2)?3:2;
  const int s0 = WS(x0), s1 = WS(x1), s2 = WS(x2);
  if (tid < 1000){
    int c0=tid/100, rem=tid-100*c0, c1=rem/10, c2=rem-10*c1;
    int base = c0*s0 + c1*s1 + c2*s2;
    LDS_RD10
    DECL_ACC4
    RSTEP_ALL
    PALL4
  }
}

// Real conditional gate W(m1,m2): matrix W_n selected by c_{m1}.
__device__ __forceinline__ void applyW4(v4f* S, const float* __restrict__ Wall, int m1, int m2, int tid){
  const int sm  = WS(m2);
  const int sm1 = WS(m1);
  int ra=-1, rb=-1;
  for (int q=0;q<4;q++) if (q!=m1 && q!=m2){ if (ra<0) ra=q; else rb=q; }
  const int sa = WS(ra), sb = WS(rb);
  if (tid < 1000){
    int n = tid/100, rem = tid-100*n, qa = rem/10, qb = rem-10*qa;
    int base = n*sm1 + qa*sa + qb*sb;
    const float* __restrict__ Mt = Wall + n*100;   // transposed W_n
    LDS_RD10
    DECL_ACC4
    RSTEP_ALL
    PALL4
  }
}

// Complex conditional gate on m2 selected by c0: WU_b[n] = W_n*UL_b.
__device__ __forceinline__ void applyWU4(v4f* S, const cxf* __restrict__ WUall, int m2, int tid){
  const int sm = WS(m2);
  const int ra = (m2==1)?2:1;
  const int rb = (m2==3)?2:3;
  const int sa = WS(ra), sb = WS(rb);
  if (tid < 1000){
    int n = tid/100, rem = tid-100*n, qa = rem/10, qb = rem-10*qa;
    int base = n*WS(0) + qa*sa + qb*sb;
    const cxf* __restrict__ U = WUall + n*100;     // transposed complex
    LDS_RD10
    DECL_ACC4
    CSTEP_ALL
    PALL4
  }
}

// Read-only measure: per-state sum_i i*|(U v)_i|^2 over this thread's fiber.
__device__ __forceinline__ v2f measure14(const v4f* S, const cxf* __restrict__ U, int m, int tid){
  const int sm = WS(m);
  const int x0 = (m==0)?1:0, x1=(m<=1)?2:1, x2=3;
  const int s0 = WS(x0), s1 = WS(x1), s2 = WS(x2);
  v2f s = {0.f, 0.f};
  if (tid < 1000){
    int c0=tid/100, rem=tid-100*c0, c1=rem/10, c2=rem-10*c1;
    int base = c0*s0 + c1*s1 + c2*s2;
    LDS_RD10
    DECL_ACC4
    CSTEP_ALL
    #define MQ4(i) { s.x += (float)(i)*(a##i.x*a##i.x + a##i.y*a##i.y); \
                     s.y += (float)(i)*(a##i.z*a##i.z + a##i.w*a##i.w); }
    MQ4(1) MQ4(2) MQ4(3) MQ4(4) MQ4(5) MQ4(6) MQ4(7) MQ4(8) MQ4(9)
    #undef MQ4
  }
  return s;
}

// Beamsplitter: photon-number-conserving anti-diagonal blocks.
__device__ __forceinline__ void applyBS4(v4f* S, const cxf* __restrict__ BSp, int m1, int m2, int tid){
  int ra=-1, rb=-1;
  for (int q=0;q<4;q++) if (q!=m1 && q!=m2){ if (ra<0) ra=q; else rb=q; }
  const int sa = WS(ra), sb = WS(rb);
  const int s1 = WS(m1), s2 = WS(m2);
  const int ds = s1 - s2;
  #pragma unroll 1
  for (int w0=0; w0<2048; w0+=NTB){
    int it = w0 + tid;
    if (it < 1900){
      int bn = it/100, rest = it-100*bn;
      int ilo = bn<10?0:bn-9, ihi = bn<10?bn:9, sz = ihi-ilo+1;
      int ca = rest/10, cb = rest-10*ca;
      int base = ca*sa + cb*sb;
      const cxf* __restrict__ Bt = BSp + bn*100;   // transposed, zero-padded
      DECL_ACC4
      int radr = base + ilo*s1 + (bn-ilo)*s2;
      int kk = 0;
      #pragma unroll 1
      for (int c=0;c<sz;c++){
        v4f vv = S[radr];
        v4f vs = __builtin_shufflevector(vv, vv, 1, 0, 3, 2);
        const v4f* Bp = (const v4f*)(Bt + kk);     // 80B row, 16B aligned
        v4f q0=Bp[0],q1=Bp[1],q2=Bp[2],q3=Bp[3],q4=Bp[4];
        CE(0,q0.x,q0.y) CE(1,q0.z,q0.w) CE(2,q1.x,q1.y) CE(3,q1.z,q1.w)
        CE(4,q2.x,q2.y) CE(5,q2.z,q2.w) CE(6,q3.x,q3.y) CE(7,q3.z,q3.w)
        CE(8,q4.x,q4.y) CE(9,q4.z,q4.w)
        radr += ds; kk += 10;
      }
      int wadr = base + ilo*s1 + (bn-ilo)*s2;
      BSTQ_ALL
    }
  }
}

__global__ __launch_bounds__(NTB)
__attribute__((amdgpu_waves_per_eu(4)))
void state_kernel(const float* __restrict__ wd, const float* __restrict__ bd,
                  const float* __restrict__ wsf, float* __restrict__ out){
  extern __shared__ __align__(16) char smem[];
  v4f* S    = (v4f*)smem;                  // 10099 v4f (161584 B)
  cxf* uv   = (cxf*)(smem + 161584);       // 2 states * 4*10 encoding vectors
  v2f* red  = (v2f*)(smem + 162224);       // 16 waves

  const float* __restrict__ V   = wsf;            // for V^T gate
  const float* __restrict__ VT  = wsf + 100;      // for V gate
  const float* __restrict__ W   = wsf + 200;
  const cxf*   __restrict__ BSm = (const cxf*)(wsf + 1200);
  const cxf*   __restrict__ UL  = (const cxf*)(wsf + 5000);
  const cxf*   __restrict__ WU  = (const cxf*)(wsf + 9800);
  const cxf*   __restrict__ uw  = (const cxf*)(wsf + U_OFF);

  const int tid = threadIdx.x, wv = tid>>6, lane = tid&63;
  const int b = blockIdx.x;                // batch items 2b, 2b+1

  if (tid < 80) uv[tid] = uw[b*80 + tid];
  __syncthreads();

  // Init: both product states, interleaved {re0,im0,re1,im1}.
  for (int e=tid; e<10000; e+=NTB){
    int c0=e/1000, r_=e-1000*c0, c1=r_/100, r2_=r_-100*c1, c2=r2_/10, c3=r2_-10*c2;
    cxf A0 = uv[c0],    B0 = uv[10+c1], C0 = uv[20+c2], D0 = uv[30+c3];
    cxf A1 = uv[40+c0], B1 = uv[50+c1], C1 = uv[60+c2], D1 = uv[70+c3];
    float pr = A0.x*B0.x - A0.y*B0.y, pi = A0.x*B0.y + A0.y*B0.x;
    float qr = pr*C0.x - pi*C0.y,  qi = pr*C0.y + pi*C0.x;
    float e0r = qr*D0.x - qi*D0.y, e0i = qr*D0.y + qi*D0.x;
    pr = A1.x*B1.x - A1.y*B1.y; pi = A1.x*B1.y + A1.y*B1.x;
    qr = pr*C1.x - pi*C1.y;  qi = pr*C1.y + pi*C1.x;
    float e1r = qr*D1.x - qi*D1.y, e1i = qr*D1.y + qi*D1.x;
    S[c0*1010 + c1*101 + c2*10 + c3] = (v4f){e0r, e0i, e1r, e1i};
  }
  __syncthreads();

  // ---------------- Layer 0 ----------------
  applyW4(S, W, 0, 1, tid); __syncthreads();
  applyW4(S, W, 0, 2, tid); __syncthreads();
  applyW4(S, W, 0, 3, tid); __syncthreads();
  apply1_r4(S, VT, 0, tid); __syncthreads();      // V0
  apply1_r4(S, V, 1, tid);  __syncthreads();      // V1^T
  applyW4(S, W, 1, 2, tid); __syncthreads();
  applyW4(S, W, 1, 3, tid); __syncthreads();
  apply1_r4(S, VT, 1, tid); __syncthreads();      // V1
  apply1_r4(S, V, 2, tid);  __syncthreads();      // V2^T
  applyW4(S, W, 2, 3, tid); __syncthreads();
  apply1_r4(S, VT, 2, tid); __syncthreads();      // V2
  applyBS4(S, BSm, 0, 1, tid); __syncthreads();
  applyBS4(S, BSm, 1, 2, tid); __syncthreads();
  applyBS4(S, BSm, 2, 3, tid); __syncthreads();
  applyBS4(S, BSm, 3, 0, tid); __syncthreads();
  apply1_c4(S, UL, 0, tid); __syncthreads();      // UL0_L0 (carries L1's V0^T)

  // ---------------- Layer 1 ----------------
  applyWU4(S, WU,        1, tid); __syncthreads();
  applyWU4(S, WU + 1000, 2, tid); __syncthreads();
  applyWU4(S, WU + 2000, 3, tid); __syncthreads();
  apply1_r4(S, VT, 0, tid); __syncthreads();      // V0
  apply1_r4(S, V, 1, tid);  __syncthreads();      // V1^T
  applyW4(S, W, 1, 2, tid); __syncthreads();
  applyW4(S, W, 1, 3, tid); __syncthreads();
  apply1_r4(S, VT, 1, tid); __syncthreads();      // V1
  apply1_r4(S, V, 2, tid);  __syncthreads();      // V2^T
  applyW4(S, W, 2, 3, tid); __syncthreads();
  apply1_r4(S, VT, 2, tid); __syncthreads();      // V2
  applyBS4(S, BSm, 0, 1, tid); __syncthreads();
  applyBS4(S, BSm, 1, 2, tid); __syncthreads();
  applyBS4(S, BSm, 2, 3, tid); __syncthreads();
  applyBS4(S, BSm, 3, 0, tid); __syncthreads();

  // Fused measurement: UL[L1,m] applied read-only; UL[L1,3] dropped.
  float w0 = wd[0], w1 = wd[1], w2 = wd[2];
  v2f m0 = measure14(S, UL + 400, 0, tid);
  v2f m1 = measure14(S, UL + 500, 1, tid);
  v2f m2 = measure14(S, UL + 600, 2, tid);
  v2f acc;
  acc.x = w0*m0.x + w1*m1.x + w2*m2.x;
  acc.y = w0*m0.y + w1*m1.y + w2*m2.y;

  for (int off=32; off; off>>=1){
    acc.x += __shfl_down(acc.x, off, 64);
    acc.y += __shfl_down(acc.y, off, 64);
  }
  if (lane == 0) red[wv] = acc;
  __syncthreads();
  if (tid == 0){
    float sx = 0.f, sy = 0.f;
    for (int i=0;i<16;i++){ sx += red[i].x; sy += red[i].y; }
    out[2*b+0] = sx + bd[0];
    out[2*b+1] = sy + bd[0];
  }
}

} // anonymous namespace

extern "C" void kernel_launch(void* const* d_in, const int* in_sizes, int n_in,
                              void* d_out, int out_size, void* d_ws, size_t ws_size,
                              hipStream_t stream){
  const float* jets   = (const float*)d_in[0];
  const float* sscale = (const float*)d_in[1];
  const float* dmag   = (const float*)d_in[2];
  const float* dphase = (const float*)d_in[3];
  const float* smag   = (const float*)d_in[4];
  const float* sphase = (const float*)d_in[5];
  const float* wd     = (const float*)d_in[6];
  const float* bd     = (const float*)d_in[7];
  float* out = (float*)d_out;
  float* wsf = (float*)d_ws;
  int B = in_sizes[0] / 12;

  (void)hipFuncSetAttribute(reinterpret_cast<const void*>(&state_kernel),
                            hipFuncAttributeMaxDynamicSharedMemorySize, SMEM_STATE);

  gates_kernel<<<12, 256, 0, stream>>>(dmag, dphase, smag, sphase, wsf);
  fuse_kernel<<<1, 512, 0, stream>>>(wsf);
  enc_kernel<<<B*4, 128, 0, stream>>>(jets, sscale, wsf);
  state_kernel<<<B/2, NTB, SMEM_STATE, stream>>>(wd, bd, wsf, out);
}